// Round 8
// baseline (20.547 us; speedup 1.0000x reference)
//
#include <hip/hip_runtime.h>
#include <hip/hip_fp16.h>
#include <cstdint>

#define NN 1536
#define DD 60
#define HH 64
#define RPB 2                 // rows per block
#define ROW_BLOCKS (NN / RPB) // 768

// prep: ABp[i][h] = half2( A[i,h]+b1[h] , B[i,h] )
//   A = embed @ W1[:60], B = embed @ W1[60:]. One contiguous 256B row per i.
__global__ __launch_bounds__(256) void prep_kernel(
    const float* __restrict__ embed, const float* __restrict__ W1,
    const float* __restrict__ b1, __half2* __restrict__ ABp) {
  int t = blockIdx.x * blockDim.x + threadIdx.x;
  int i = t >> 6, h = t & 63;
  float accA = b1[h], accB = 0.f;
  const float* er = embed + i * DD;
#pragma unroll
  for (int d = 0; d < DD; ++d) {
    float e = er[d];
    accA += e * W1[d * HH + h];
    accB += e * W1[(DD + d) * HH + h];
  }
  ABp[i * HH + h] = __floats2half2_rn(accA, accB);
}

// row kernel: block owns RPB rows of adj/out. adj load -> wave-scan
// compaction into LDS jlist -> 2-threads-per-entry gate compute (even: q0-7
// + u1 from LDS noise rows; odd: q8-15 + scattered u2), shfl_xor combine ->
// LDS rowbuf -> coalesced row writeout. adj nonzeros are exactly 1.0f.
__global__ __launch_bounds__(256) void row_kernel(
    const __half2* __restrict__ ABp, const float* __restrict__ W2,
    const float* __restrict__ b2, const float* __restrict__ adj,
    const float* __restrict__ noise, const int* __restrict__ tmp,
    float* __restrict__ out) {
  __shared__ float rowbuf[RPB * NN];               // 12 KB
  __shared__ float noiseL[RPB * NN];               // 12 KB
  __shared__ float w2L[HH];                        // 256 B
  __shared__ __align__(16) __half2 ABL[RPB * HH];  // 512 B
  __shared__ unsigned short jlist[RPB * NN];       // 6 KB
  __shared__ int wsum[4], wbase[4], njtot;

  const int tid = threadIdx.x;
  const int lane = tid & 63, wid = tid >> 6;
  const int i0 = blockIdx.x * RPB;

  // issue adj row loads early (3 coalesced float4 per thread)
  const float4* a4 = (const float4*)(adj + i0 * NN);
  float4 v0 = a4[tid + 0 * 256];
  float4 v1 = a4[tid + 1 * 256];
  float4 v2 = a4[tid + 2 * 256];

  // stage noise rows (coalesced) into LDS
  const float4* n4 = (const float4*)(noise + i0 * NN);
  float4* nl4 = (float4*)noiseL;
  nl4[tid + 0 * 256] = n4[tid + 0 * 256];
  nl4[tid + 1 * 256] = n4[tid + 1 * 256];
  nl4[tid + 2 * 256] = n4[tid + 2 * 256];

  if (tid < HH) w2L[tid] = W2[tid];
  if (tid >= 64 && tid < 64 + RPB * HH) {
    int x = tid - 64;
    ABL[x] = ABp[i0 * HH + x];
  }

  // zero rowbuf
  float4* rb4 = (float4*)rowbuf;
  float4 z = make_float4(0.f, 0.f, 0.f, 0.f);
  rb4[tid + 0 * 256] = z;
  rb4[tid + 1 * 256] = z;
  rb4[tid + 2 * 256] = z;

  // nonzero mask (both triangles: block computes its full rows)
  unsigned mask = 0;
  mask |= (v0.x != 0.f) ? 0x001u : 0u;
  mask |= (v0.y != 0.f) ? 0x002u : 0u;
  mask |= (v0.z != 0.f) ? 0x004u : 0u;
  mask |= (v0.w != 0.f) ? 0x008u : 0u;
  mask |= (v1.x != 0.f) ? 0x010u : 0u;
  mask |= (v1.y != 0.f) ? 0x020u : 0u;
  mask |= (v1.z != 0.f) ? 0x040u : 0u;
  mask |= (v1.w != 0.f) ? 0x080u : 0u;
  mask |= (v2.x != 0.f) ? 0x100u : 0u;
  mask |= (v2.y != 0.f) ? 0x200u : 0u;
  mask |= (v2.z != 0.f) ? 0x400u : 0u;
  mask |= (v2.w != 0.f) ? 0x800u : 0u;

  int c = __popc(mask);
  int incl = c;
#pragma unroll
  for (int off = 1; off < 64; off <<= 1) {
    int t = __shfl_up(incl, off, 64);
    if (lane >= off) incl += t;
  }
  if (lane == 63) wsum[wid] = incl;
  __syncthreads();
  if (tid == 0) {
    int tot = 0;
#pragma unroll
    for (int w = 0; w < 4; ++w) { wbase[w] = tot; tot += wsum[w]; }
    njtot = tot;
  }
  __syncthreads();

  int o = wbase[wid] + (incl - c);
  unsigned mm = mask;
  while (mm) {
    int b = __ffs((int)mm) - 1;
    mm &= mm - 1;
    int f = ((b >> 2) * 256 + tid) * 4 + (b & 3);
    int r = f / NN;
    int j = f - r * NN;
    jlist[o++] = (unsigned short)((r << 11) | j);
  }

  __syncthreads();

  const int n = njtot;
  const float invb = 1.f / (float)(*tmp);
  const float bb = b2[0];
  const int half = tid & 1;

  for (int base = 0; base < 2 * n; base += 256) {
    int k = (base + tid) >> 1;  // 2 consecutive threads per entry
    if (k < n) {
      unsigned e = jlist[k];
      int r = (int)(e >> 11);
      int j = (int)(e & 2047u);
      int i = i0 + r;
      const float4* G = (const float4*)(ABp + j * HH) + half * 8;
      const float4* L = (const float4*)(ABL + r * HH) + half * 8;
      float pij = 0.f, pji = 0.f;
#pragma unroll
      for (int q = 0; q < 8; ++q) {
        float4 g = G[q];
        float4 l = L[q];
        const __half2* gh = (const __half2*)&g;
        const __half2* lh = (const __half2*)&l;
#pragma unroll
        for (int s = 0; s < 4; ++s) {
          float2 fj = __half22float2(gh[s]);  // (A_j, B_j)
          float2 fi = __half22float2(lh[s]);  // (A_i, B_i)
          float w = w2L[(half * 8 + q) * 4 + s];
          pij += fmaxf(fi.x + fj.y, 0.f) * w;
          pji += fmaxf(fj.x + fi.y, 0.f) * w;
        }
      }
      // combine half-dots across the thread pair
      pij += __shfl_xor(pij, 1, 64);
      pji += __shfl_xor(pji, 1, 64);
      // even thread: direction (i,j), u1 from LDS; odd: (j,i), scattered u2
      float u, la;
      if (half == 0) {
        u = noiseL[r * NN + j];
        la = pij + bb;
      } else {
        u = noise[j * NN + i];
        la = pji + bb;
      }
      float lg = __logf(u) - __logf(1.f - u);
      float g = 1.f / (1.f + __expf(-(lg + la) * invb));
      float go = __shfl_xor(g, 1, 64);
      if (half == 0) rowbuf[r * NN + j] = 0.5f * (g + go);
    }
  }

  __syncthreads();

  float4* o4 = (float4*)(out + i0 * NN);
  o4[tid + 0 * 256] = rb4[tid + 0 * 256];
  o4[tid + 1 * 256] = rb4[tid + 1 * 256];
  o4[tid + 2 * 256] = rb4[tid + 2 * 256];
}

extern "C" void kernel_launch(void* const* d_in, const int* in_sizes, int n_in,
                              void* d_out, int out_size, void* d_ws,
                              size_t ws_size, hipStream_t stream) {
  const float* embed = (const float*)d_in[0];
  const float* W1 = (const float*)d_in[1];
  const float* b1 = (const float*)d_in[2];
  const float* W2 = (const float*)d_in[3];
  const float* b2 = (const float*)d_in[4];
  const float* adj = (const float*)d_in[5];
  const float* noise = (const float*)d_in[6];
  const int* tmp = (const int*)d_in[7];
  float* out = (float*)d_out;

  __half2* ABp = (__half2*)d_ws;  // NN*HH half2 = 384 KB

  hipLaunchKernelGGL(prep_kernel, dim3(NN * HH / 256), dim3(256), 0, stream,
                     embed, W1, b1, ABp);
  hipLaunchKernelGGL(row_kernel, dim3(ROW_BLOCKS), dim3(256), 0, stream, ABp,
                     W2, b2, adj, noise, tmp, out);
}